// Round 3
// baseline (973.878 us; speedup 1.0000x reference)
//
#include <hip/hip_runtime.h>
#include <math.h>

#define D 256
#define NSEG 8192
#define RROWS 20   // cached rows per wave (80/block = mean+2sigma); 80 VGPRs

typedef float f4_t __attribute__((ext_vector_type(4)));

// ---------- setup: segment starts (replaces per-block binary search) ----------
__global__ __launch_bounds__(256) void seg_starts_kernel(
        const int* __restrict__ obj, int T, int* __restrict__ starts) {
    const int i = blockIdx.x * blockDim.x + threadIdx.x;
    if (i >= T) return;
    const int cur  = obj[i];
    const int prev = (i == 0) ? -1 : obj[i - 1];
    for (int s = prev + 1; s <= cur; ++s) starts[s] = i;   // fills gaps (empty segs)
    if (i == T - 1) {
        for (int s = cur + 1; s <= NSEG; ++s) starts[s] = T;
    }
}

__device__ __forceinline__ int lower_bound_dev(const int* __restrict__ a, int n, int key) {
    int lo = 0, hi = n;
    while (lo < hi) {
        int mid = (lo + hi) >> 1;
        if (a[mid] < key) lo = mid + 1; else hi = mid;
    }
    return lo;
}

__device__ __forceinline__ float dot4(const float4 a, const float4 b) {
    return a.x * b.x + a.y * b.y + a.z * b.z + a.w * b.w;
}

__device__ __forceinline__ float4 ld4(const float* p) {
    return *reinterpret_cast<const float4*>(p);
}

// One block (256 threads = 4 waves) per segment. Fully fused:
//   pass 1: load segment rows ONCE into registers (20 independent loads in
//           flight per wave) + segment sum. Tail (>80 rows, ~2% of segs) streams.
//   proj  : tg = tanh((s @ W) / cnt). wave w owns k-range [64w,64w+64),
//           lane owns 4 adjacent cols -> float4 W loads (L2-resident W)
//   pass 2: PURE VALU from the register cache (no memory): score + weighted sum
//   pass 3: broadcast rep (nontemporal stores; out never re-read)
template <bool USE_STARTS>
__global__ __launch_bounds__(256, 4) void fused_seg_kernel(
        const float* __restrict__ emb,
        const float* __restrict__ W,
        const int*   __restrict__ obj, int T,
        const int*   __restrict__ starts,
        float* __restrict__ out) {
    const int seg = blockIdx.x;
    int start, end;
    if (USE_STARTS) {
        start = starts[seg];          // uniform -> scalar loads
        end   = starts[seg + 1];
    } else {
        start = lower_bound_dev(obj, T, seg);
        end   = lower_bound_dev(obj, T, seg + 1);
    }
    if (start >= end) return;   // empty segment

    const int tid  = threadIdx.x;
    const int lane = tid & 63;
    const int w    = tid >> 6;
    const int col  = lane * 4;

    __shared__ float sm[4][D];   // cross-wave reduction scratch
    __shared__ float sv[D];      // segment sum
    __shared__ float tg[D];      // transformed global context

    const float* ebase = emb + col;
    const int rbase = start + w;

    // ---- pass 1: load rows into registers + segment sum ----
    // Invalid slots are zero-filled: pass 2 is then branch-free (their
    // contribution is exactly 0 regardless of the sigmoid value).
    float4 cache[RROWS];
    #pragma unroll
    for (int i = 0; i < RROWS; ++i) {
        const int r = rbase + 4 * i;              // wave-uniform condition
        cache[i] = (r < end) ? ld4(ebase + (size_t)r * D)
                             : make_float4(0.f, 0.f, 0.f, 0.f);
    }
    float4 acc = make_float4(0.f, 0.f, 0.f, 0.f);
    #pragma unroll
    for (int i = 0; i < RROWS; ++i) {
        acc.x += cache[i].x; acc.y += cache[i].y;
        acc.z += cache[i].z; acc.w += cache[i].w;
    }
    // rare tail (segment longer than 4*RROWS rows): stream
    for (int r = rbase + 4 * RROWS; r < end; r += 4) {
        const float4 e = ld4(ebase + (size_t)r * D);
        acc.x += e.x; acc.y += e.y; acc.z += e.z; acc.w += e.w;
    }
    *reinterpret_cast<float4*>(&sm[w][col]) = acc;
    __syncthreads();
    sv[tid] = sm[0][tid] + sm[1][tid] + sm[2][tid] + sm[3][tid];
    __syncthreads();

    // ---- projection: wave w handles k in [64w, 64w+64); lane handles
    //      columns [col, col+4) -> coalesced float4 row-slices of W.
    const float inv = 1.0f / (float)(end - start);
    float4 p4 = make_float4(0.f, 0.f, 0.f, 0.f);
    {
        const float* Wp = W + (size_t)(64 * w) * D + col;
        const float* svp = &sv[64 * w];
        #pragma unroll 16
        for (int kk = 0; kk < 64; ++kk) {
            const float  s  = svp[kk];                 // LDS broadcast (uniform)
            const float4 wr = ld4(Wp + (size_t)kk * D);
            p4.x += s * wr.x; p4.y += s * wr.y;
            p4.z += s * wr.z; p4.w += s * wr.w;
        }
    }
    // sm is free again (sv consumed it before the last barrier)
    *reinterpret_cast<float4*>(&sm[w][col]) = p4;
    __syncthreads();
    const float pj = sm[0][tid] + sm[1][tid] + sm[2][tid] + sm[3][tid];
    tg[tid] = tanhf(pj * inv);
    __syncthreads();
    const float4 tg4 = ld4(&tg[col]);

    // ---- pass 2: score + weighted sum, PURE VALU from register cache ----
    // 20 independent shfl-reduce chains; branch-free, compiler interleaves.
    float4 racc = make_float4(0.f, 0.f, 0.f, 0.f);
    #pragma unroll
    for (int i = 0; i < RROWS; ++i) {
        float pd = dot4(cache[i], tg4);
        #pragma unroll
        for (int off = 32; off >= 1; off >>= 1) pd += __shfl_xor(pd, off, 64);
        const float s = 1.0f / (1.0f + __expf(-pd));
        racc.x += cache[i].x * s; racc.y += cache[i].y * s;
        racc.z += cache[i].z * s; racc.w += cache[i].w * s;
    }
    // rare tail: re-read (LLC-hot) and reduce
    for (int r = rbase + 4 * RROWS; r < end; r += 4) {
        const float4 e = ld4(ebase + (size_t)r * D);
        float pd = dot4(e, tg4);
        #pragma unroll
        for (int off = 32; off >= 1; off >>= 1) pd += __shfl_xor(pd, off, 64);
        const float s = 1.0f / (1.0f + __expf(-pd));
        racc.x += e.x * s; racc.y += e.y * s;
        racc.z += e.z * s; racc.w += e.w * s;
    }
    *reinterpret_cast<float4*>(&sm[w][col]) = racc;
    __syncthreads();
    sm[0][tid] = sm[0][tid] + sm[1][tid] + sm[2][tid] + sm[3][tid];
    __syncthreads();
    const float4 rep4 = ld4(&sm[0][col]);
    const f4_t repv = { rep4.x, rep4.y, rep4.z, rep4.w };

    // ---- pass 3: broadcast rep to every token row (nontemporal) ----
    {
        float* obase = out + col;
        int r = rbase;
        for (; r + 12 < end; r += 16) {
            __builtin_nontemporal_store(repv, reinterpret_cast<f4_t*>(obase + (size_t)r * D));
            __builtin_nontemporal_store(repv, reinterpret_cast<f4_t*>(obase + (size_t)(r + 4) * D));
            __builtin_nontemporal_store(repv, reinterpret_cast<f4_t*>(obase + (size_t)(r + 8) * D));
            __builtin_nontemporal_store(repv, reinterpret_cast<f4_t*>(obase + (size_t)(r + 12) * D));
        }
        for (; r < end; r += 4) {
            __builtin_nontemporal_store(repv, reinterpret_cast<f4_t*>(obase + (size_t)r * D));
        }
    }
}

extern "C" void kernel_launch(void* const* d_in, const int* in_sizes, int n_in,
                              void* d_out, int out_size, void* d_ws, size_t ws_size,
                              hipStream_t stream) {
    const float* emb = (const float*)d_in[0];
    const float* W   = (const float*)d_in[1];
    const int*   obj = (const int*)d_in[2];
    const int T = in_sizes[2];
    float* out = (float*)d_out;

    if (d_ws != nullptr && ws_size >= (size_t)(NSEG + 1) * sizeof(int)) {
        int* starts = (int*)d_ws;
        seg_starts_kernel<<<(T + 255) / 256, 256, 0, stream>>>(obj, T, starts);
        fused_seg_kernel<true><<<NSEG, 256, 0, stream>>>(emb, W, obj, T, starts, out);
    } else {
        fused_seg_kernel<false><<<NSEG, 256, 0, stream>>>(emb, W, obj, T, nullptr, out);
    }
}